// Round 17
// baseline (260.744 us; speedup 1.0000x reference)
//
#include <hip/hip_runtime.h>
#include <hip/hip_cooperative_groups.h>
#include <hip/hip_bf16.h>
#include <math.h>

namespace cg = cooperative_groups;

#define IN_DIM 128
#define C_DIM 64
#define BKT_CHUNK 4096

typedef short bf16x8 __attribute__((ext_vector_type(8)));
typedef float f32x4 __attribute__((ext_vector_type(4)));

static __device__ __forceinline__ unsigned short f2bf(float f) {
    unsigned int u = __float_as_uint(f);
    u += 0x7FFFu + ((u >> 16) & 1u);          // round-to-nearest-even
    return (unsigned short)(u >> 16);
}
static __device__ __forceinline__ float bf2f(unsigned short h) {
    return __uint_as_float(((unsigned int)h) << 16);
}

// LDS overlay: a block is in exactly one phase-role at a time.
struct SmemG { unsigned short WT[2][64][128]; };                    // 32768 B
struct SmemB { int cnt[128]; int run[128]; int cur[128]; };         //  1536 B
struct SmemS { int cnt[512]; int off[513]; int cur[512];
               int wsum[4]; float si_l[512]; };                     //  8212 B
union  SmemU { SmemG g; SmemB b; SmemS s; };                        // 32768 B

// ---------------------------------------------------------------------------
// ONE cooperative kernel, three phases separated by grid.sync():
//  P1: blocks [0,GB) GEMM (g=x@W bf16-MFMA 3-term + score dots);
//      blocks [GB,GB+BB) bucket-partition edges (512 nodes/bucket).
//  P2: block per bucket: LDS count/scan -> row_start/row_end; scatter
//      records with PRECOMPUTED bf16 weight: rec = (bf16(w)<<16)|src.
//  P3: grid-strided aggregate: wave per node, 8 edges x 8 lanes,
//      max-free softmax (num/den), bias + ReLU.
// ---------------------------------------------------------------------------
__global__ __launch_bounds__(256) void k_fused(
    const float* __restrict__ x, const float* __restrict__ W,
    const float* __restrict__ corrs,
    const float* __restrict__ att_i, const float* __restrict__ att_j,
    const float* __restrict__ att_em_i, const float* __restrict__ att_em_j,
    unsigned short* __restrict__ g_bf, float* __restrict__ s_i, float* __restrict__ s_j,
    const int* __restrict__ src, const int* __restrict__ dst,
    int N, int E, int GB, int BB, int NB, int CAP,
    int* __restrict__ bucket_cnt, unsigned int* __restrict__ staging,
    unsigned int* __restrict__ edge_rec,
    int* __restrict__ row_start, int* __restrict__ row_end,
    const float* __restrict__ bias, float* __restrict__ out)
{
    __shared__ SmemU sm;
    cg::grid_group grid = cg::this_grid();
    int tid = threadIdx.x;
    int T = E + N;

    // ======================= PHASE 1: GEMM || bucket =======================
    for (int vb = blockIdx.x; vb < GB + BB; vb += gridDim.x) {
        if (vb >= GB) {
            // ---------------- bucket part ----------------
            if (tid < 128) sm.b.cnt[tid] = 0;
            __syncthreads();
            int base = (vb - GB) * BKT_CHUNK;
#pragma unroll
            for (int k = 0; k < BKT_CHUNK / 256; ++k) {
                int i = base + k * 256 + tid;
                if (i < T) {
                    int d = (i < E) ? dst[i] : (i - E);
                    atomicAdd(&sm.b.cnt[d >> 9], 1);
                }
            }
            __syncthreads();
            if (tid < NB && sm.b.cnt[tid] > 0)
                sm.b.run[tid] = atomicAdd(&bucket_cnt[tid], sm.b.cnt[tid]);
            if (tid < 128) sm.b.cur[tid] = 0;
            __syncthreads();
#pragma unroll
            for (int k = 0; k < BKT_CHUNK / 256; ++k) {
                int i = base + k * 256 + tid;
                if (i < T) {
                    int d, s;
                    if (i < E) { d = dst[i]; s = src[i]; }
                    else       { d = i - E; s = d; }      // self loop
                    int b = d >> 9;
                    int ofs = atomicAdd(&sm.b.cur[b], 1);
                    int pos = sm.b.run[b] + ofs;
                    if (pos < CAP)
                        staging[(size_t)b * CAP + pos] =
                            (unsigned)s | ((unsigned)(d & 511) << 16);
                }
            }
        } else {
            // ---------------- GEMM part ----------------
#pragma unroll
            for (int p = 0; p < 8; ++p) {
                int f = p * 1024 + tid * 4;               // flat into W[128][64]
                f32x4 w4 = *(const f32x4*)(W + f);
                int k  = f >> 6;
                int c0 = f & 63;
#pragma unroll
                for (int i = 0; i < 4; ++i) {
                    int c = c0 + i;
                    float wv2 = w4[i];
                    unsigned short hi = f2bf(wv2);
                    unsigned short lo = f2bf(wv2 - bf2f(hi));
                    int ks = k ^ ((c & 7) << 3);
                    sm.g.WT[0][c][ks] = hi;
                    sm.g.WT[1][c][ks] = lo;
                }
            }
            __syncthreads();

            int wv = tid >> 6, lane = tid & 63;
            int mrow = lane & 15;
            int kgrp = lane >> 4;
            int row  = vb * 64 + wv * 16 + mrow;
            int rowc = min(row, N - 1);

            f32x4 acc[4];
#pragma unroll
            for (int t = 0; t < 4; ++t) { f32x4 z = {0.f, 0.f, 0.f, 0.f}; acc[t] = z; }

            f32x4 xa[4], xb[4];
#pragma unroll
            for (int s = 0; s < 4; ++s) {
                const float* xp = x + (size_t)rowc * IN_DIM + s * 32 + kgrp * 8;
                xa[s] = *(const f32x4*)xp;
                xb[s] = *(const f32x4*)(xp + 4);
            }

#pragma unroll
            for (int s = 0; s < 4; ++s) {
                bf16x8 ah, al;
#pragma unroll
                for (int i = 0; i < 4; ++i) {
                    unsigned short h0 = f2bf(xa[s][i]);
                    ah[i]     = (short)h0;
                    al[i]     = (short)f2bf(xa[s][i] - bf2f(h0));
                    unsigned short h1 = f2bf(xb[s][i]);
                    ah[4 + i] = (short)h1;
                    al[4 + i] = (short)f2bf(xb[s][i] - bf2f(h1));
                }
                int kbase = s * 32 + kgrp * 8;
#pragma unroll
                for (int t = 0; t < 4; ++t) {
                    int c  = t * 16 + mrow;
                    int ks = kbase ^ ((c & 7) << 3);
                    bf16x8 bh = *(const bf16x8*)&sm.g.WT[0][c][ks];
                    bf16x8 bl = *(const bf16x8*)&sm.g.WT[1][c][ks];
                    acc[t] = __builtin_amdgcn_mfma_f32_16x16x32_bf16(ah, bh, acc[t], 0, 0, 0);
                    acc[t] = __builtin_amdgcn_mfma_f32_16x16x32_bf16(ah, bl, acc[t], 0, 0, 0);
                    acc[t] = __builtin_amdgcn_mfma_f32_16x16x32_bf16(al, bh, acc[t], 0, 0, 0);
                }
            }

            float ai[4], aj[4], aei[4], aej[4];
#pragma unroll
            for (int t = 0; t < 4; ++t) {
                ai[t]  = att_i[t * 16 + mrow];
                aj[t]  = att_j[t * 16 + mrow];
                aei[t] = att_em_i[t * 16 + mrow];
                aej[t] = att_em_j[t * 16 + mrow];
            }
            int crow_base = vb * 64 + wv * 16 + (lane >> 4) * 4;
#pragma unroll
            for (int r = 0; r < 4; ++r) {
                int grow  = crow_base + r;
                int growc = min(grow, N - 1);
                float vi = 0.f, vj = 0.f;
                ushort4 hv;
#pragma unroll
                for (int t = 0; t < 4; ++t) {
                    float gv = acc[t][r];
                    float cv = corrs[(size_t)growc * 64 + t * 16 + mrow];
                    unsigned short h = f2bf(gv);
                    if (t == 0) hv.x = h; else if (t == 1) hv.y = h;
                    else if (t == 2) hv.z = h; else hv.w = h;
                    vi = fmaf(gv, ai[t], fmaf(cv, aei[t], vi));
                    vj = fmaf(gv, aj[t], fmaf(cv, aej[t], vj));
                }
                if (grow < N)
                    *(ushort4*)(g_bf + (size_t)grow * C_DIM + mrow * 4) = hv;
#pragma unroll
                for (int o = 1; o < 16; o <<= 1) {
                    vi += __shfl_xor(vi, o);
                    vj += __shfl_xor(vj, o);
                }
                if (mrow == 0 && grow < N) { s_i[grow] = vi; s_j[grow] = vj; }
            }
        }
        __syncthreads();      // LDS reuse safety across virtual blocks
    }

    grid.sync();

    // ======================= PHASE 2: scatter ==============================
    for (int b = blockIdx.x; b < NB; b += gridDim.x) {
        int t = tid;
        int lo = b << 9;
        int hi = min(lo + 512, N);
        int bcnt = min(bucket_cnt[b], CAP);
        const unsigned int* sb = staging + (size_t)b * CAP;

        sm.s.cnt[2 * t] = 0; sm.s.cnt[2 * t + 1] = 0;
        if (lo + 2 * t     < N) sm.s.si_l[2 * t]     = s_i[lo + 2 * t];
        if (lo + 2 * t + 1 < N) sm.s.si_l[2 * t + 1] = s_i[lo + 2 * t + 1];
        __syncthreads();

        for (int r = t; r < bcnt; r += 256)
            atomicAdd(&sm.s.cnt[(sb[r] >> 16) & 511], 1);
        __syncthreads();

        int a0 = sm.s.cnt[2 * t], a1 = sm.s.cnt[2 * t + 1];
        int s = a0 + a1;
        int lane = t & 63, wv = t >> 6;
        int incl = s;
#pragma unroll
        for (int o = 1; o < 64; o <<= 1) {
            int u = __shfl_up(incl, o);
            if (lane >= o) incl += u;
        }
        if (lane == 63) sm.s.wsum[wv] = incl;
        __syncthreads();
        int woff = 0;
        for (int w = 0; w < wv; ++w) woff += sm.s.wsum[w];
        int ex = woff + incl - s;
        sm.s.off[2 * t] = ex;       sm.s.off[2 * t + 1] = ex + a0;
        sm.s.cur[2 * t] = ex;       sm.s.cur[2 * t + 1] = ex + a0;
        if (t == 255) sm.s.off[512] = woff + incl;
        __syncthreads();

        int rawb = b * CAP;
        for (int i = t; i < hi - lo; i += 256) {
            row_start[lo + i] = rawb + sm.s.off[i];
            row_end[lo + i]   = rawb + sm.s.off[i + 1];
        }
        for (int r = t; r < bcnt; r += 256) {
            unsigned int rec = sb[r];
            int dl   = (rec >> 16) & 511;
            int srcn = rec & 0xFFFFu;
            float a = sm.s.si_l[dl] + s_j[srcn];
            a = (a > 0.f) ? a : 0.2f * a;
            float w = __expf(a);
            int slot = atomicAdd(&sm.s.cur[dl], 1);
            edge_rec[rawb + slot] = ((unsigned)f2bf(w) << 16) | (unsigned)srcn;
        }
        __syncthreads();      // protect si_l/cnt reuse on next iteration
    }

    grid.sync();

    // ======================= PHASE 3: aggregate ============================
    {
        int wave = tid >> 6, lane = tid & 63;
        int grp = lane >> 3;          // edge slot 0..7
        int cl  = lane & 7;           // owns permuted slots cl*8 .. cl*8+7
        int nq = (N + 3) >> 2;
        for (int q = blockIdx.x; q < nq; q += gridDim.x) {
            int n = q * 4 + wave;
            if (n >= N) continue;
            int start = row_start[n];
            int end   = row_end[n];

            float a0 = 0.f, a1 = 0.f, a2 = 0.f, a3 = 0.f;
            float a4 = 0.f, a5 = 0.f, a6 = 0.f, a7 = 0.f, den = 0.f;
#pragma unroll 2
            for (int e0 = start; e0 < end; e0 += 8) {
                int e = e0 + grp;
                if (e < end) {
                    unsigned int rec = edge_rec[e];
                    int   srcn = rec & 0xFFFFu;
                    float w    = bf2f((unsigned short)(rec >> 16));
                    const ushort4* gp = (const ushort4*)(g_bf + (size_t)srcn * C_DIM + (cl << 3));
                    ushort4 g0 = gp[0];
                    ushort4 g1 = gp[1];
                    a0 = fmaf(w, bf2f(g0.x), a0);
                    a1 = fmaf(w, bf2f(g0.y), a1);
                    a2 = fmaf(w, bf2f(g0.z), a2);
                    a3 = fmaf(w, bf2f(g0.w), a3);
                    a4 = fmaf(w, bf2f(g1.x), a4);
                    a5 = fmaf(w, bf2f(g1.y), a5);
                    a6 = fmaf(w, bf2f(g1.z), a6);
                    a7 = fmaf(w, bf2f(g1.w), a7);
                    den += w;
                }
            }
#pragma unroll
            for (int o = 8; o < 64; o <<= 1) {
                a0  += __shfl_xor(a0, o);
                a1  += __shfl_xor(a1, o);
                a2  += __shfl_xor(a2, o);
                a3  += __shfl_xor(a3, o);
                a4  += __shfl_xor(a4, o);
                a5  += __shfl_xor(a5, o);
                a6  += __shfl_xor(a6, o);
                a7  += __shfl_xor(a7, o);
                den += __shfl_xor(den, o);
            }
            if (grp == 0) {
                float inv = 1.f / (den + 1e-16f);
                float av[8] = {a0, a1, a2, a3, a4, a5, a6, a7};
                float* op = out + (size_t)n * C_DIM;
#pragma unroll
                for (int j = 0; j < 8; ++j) {
                    int p  = (cl << 3) + j;                 // permuted slot
                    int ch = ((p & 3) << 4) + (p >> 2);     // real channel
                    op[ch] = fmaxf(fmaf(av[j], inv, bias[ch]), 0.f);
                }
            }
        }
    }
}

// ---------------------------------------------------------------------------
extern "C" void kernel_launch(void* const* d_in, const int* in_sizes, int n_in,
                              void* d_out, int out_size, void* d_ws, size_t ws_size,
                              hipStream_t stream)
{
    const float* x        = (const float*)d_in[0];
    const int*   eidx     = (const int*)  d_in[1];
    const float* corrs    = (const float*)d_in[2];
    const float* W        = (const float*)d_in[3];
    const float* att_i    = (const float*)d_in[4];
    const float* att_j    = (const float*)d_in[5];
    const float* att_em_i = (const float*)d_in[6];
    const float* att_em_j = (const float*)d_in[7];
    const float* bias     = (const float*)d_in[8];
    float* out = (float*)d_out;

    int N = in_sizes[0] / IN_DIM;
    int E = in_sizes[1] / 2;
    const int* src = eidx;
    const int* dst = eidx + E;

    int T  = E + N;
    int NB = (N + 511) >> 9;                       // 512 nodes per bucket
    int CAP = ((T + NB - 1) / NB);
    CAP = CAP + CAP / 4;                           // 1.25x slack
    CAP = (CAP + 63) & ~63;

    char* ws = (char*)d_ws;
    size_t off = 0;
    auto alloc = [&](size_t bytes) -> void* {
        void* p = ws + off;
        off += (bytes + 255) & ~(size_t)255;
        return p;
    };
    unsigned short* g_bf = (unsigned short*)alloc((size_t)N * C_DIM * sizeof(unsigned short));
    float* s_i       = (float*)alloc((size_t)N * sizeof(float));
    float* s_j       = (float*)alloc((size_t)N * sizeof(float));
    unsigned int* staging  = (unsigned int*)alloc((size_t)NB * CAP * sizeof(unsigned int));
    unsigned int* edge_rec = (unsigned int*)alloc((size_t)NB * CAP * sizeof(unsigned int));
    int*   row_start = (int*)alloc((size_t)N * sizeof(int));
    int*   row_end   = (int*)alloc((size_t)N * sizeof(int));
    int*   bucket_cnt= (int*)alloc(128 * sizeof(int));
    (void)ws_size; (void)n_in; (void)out_size;

    hipMemsetAsync(bucket_cnt, 0, 128 * sizeof(int), stream);

    int GB = (N + 63) / 64;                        // gemm virtual blocks
    int BB = (T + BKT_CHUNK - 1) / BKT_CHUNK;      // bucket virtual blocks

    // Co-residency bound for the cooperative launch (MI355X: 256 CUs).
    int occ = 0;
    hipOccupancyMaxActiveBlocksPerMultiprocessor(&occ, k_fused, 256, 0);
    if (occ < 1) occ = 1;
    int maxco = occ * 256;
    int need  = GB + BB;
    int gridn = need < maxco ? need : maxco;

    void* args[] = {
        (void*)&x, (void*)&W, (void*)&corrs,
        (void*)&att_i, (void*)&att_j, (void*)&att_em_i, (void*)&att_em_j,
        (void*)&g_bf, (void*)&s_i, (void*)&s_j,
        (void*)&src, (void*)&dst,
        (void*)&N, (void*)&E, (void*)&GB, (void*)&BB, (void*)&NB, (void*)&CAP,
        (void*)&bucket_cnt, (void*)&staging, (void*)&edge_rec,
        (void*)&row_start, (void*)&row_end,
        (void*)&bias, (void*)&out
    };
    hipLaunchCooperativeKernel((void*)k_fused, dim3(gridn), dim3(256),
                               args, 0, stream);
}

// Round 18
// 259.492 us; speedup vs baseline: 1.0048x; 1.0048x over previous
//
#include <hip/hip_runtime.h>
#include <hip/hip_cooperative_groups.h>
#include <hip/hip_bf16.h>
#include <math.h>

namespace cg = cooperative_groups;

#define IN_DIM 128
#define C_DIM 64
#define BKT_CHUNK 4096

typedef short bf16x8 __attribute__((ext_vector_type(8)));
typedef float f32x4 __attribute__((ext_vector_type(4)));

static __device__ __forceinline__ unsigned short f2bf(float f) {
    unsigned int u = __float_as_uint(f);
    u += 0x7FFFu + ((u >> 16) & 1u);          // round-to-nearest-even
    return (unsigned short)(u >> 16);
}
static __device__ __forceinline__ float bf2f(unsigned short h) {
    return __uint_as_float(((unsigned int)h) << 16);
}

// LDS overlay: a block is in exactly one phase-role at a time.
// ALIGNED(16) IS LOAD-BEARING: without it the bf16x8 WT reads lose their
// provable 16B alignment and compile to 8x ds_read_u16 (R17: 5.66M bank
// conflicts, 3x kernel regression).
struct SmemG { unsigned short WT[2][64][128]; };                    // 32768 B
struct SmemB { int cnt[128]; int run[128]; int cur[128]; };         //  1536 B
struct SmemS { int cnt[512]; int off[513]; int cur[512];
               int wsum[4]; float si_l[512]; };                     //  8212 B
union __attribute__((aligned(16))) SmemU { SmemG g; SmemB b; SmemS s; };

// ---------------------------------------------------------------------------
// ONE cooperative kernel, three phases separated by grid.sync():
//  P1: blocks [0,GB) GEMM (g=x@W bf16-MFMA 3-term + score dots);
//      blocks [GB,GB+BB) bucket-partition edges (512 nodes/bucket).
//  P2: block per bucket: LDS count/scan -> row_start/row_end; scatter
//      records with PRECOMPUTED bf16 weight: rec = (bf16(w)<<16)|src.
//  P3: grid-strided aggregate: wave per node, 8 edges x 8 lanes,
//      max-free softmax (num/den), bias + ReLU.
// ---------------------------------------------------------------------------
__global__ __launch_bounds__(256) void k_fused(
    const float* __restrict__ x, const float* __restrict__ W,
    const float* __restrict__ corrs,
    const float* __restrict__ att_i, const float* __restrict__ att_j,
    const float* __restrict__ att_em_i, const float* __restrict__ att_em_j,
    unsigned short* __restrict__ g_bf, float* __restrict__ s_i, float* __restrict__ s_j,
    const int* __restrict__ src, const int* __restrict__ dst,
    int N, int E, int GB, int BB, int NB, int CAP,
    int* __restrict__ bucket_cnt, unsigned int* __restrict__ staging,
    unsigned int* __restrict__ edge_rec,
    int* __restrict__ row_start, int* __restrict__ row_end,
    const float* __restrict__ bias, float* __restrict__ out)
{
    __shared__ SmemU sm;
    cg::grid_group grid = cg::this_grid();
    int tid = threadIdx.x;
    int T = E + N;

    // ======================= PHASE 1: GEMM || bucket =======================
    for (int vb = blockIdx.x; vb < GB + BB; vb += gridDim.x) {
        if (vb >= GB) {
            // ---------------- bucket part ----------------
            if (tid < 128) sm.b.cnt[tid] = 0;
            __syncthreads();
            int base = (vb - GB) * BKT_CHUNK;
#pragma unroll
            for (int k = 0; k < BKT_CHUNK / 256; ++k) {
                int i = base + k * 256 + tid;
                if (i < T) {
                    int d = (i < E) ? dst[i] : (i - E);
                    atomicAdd(&sm.b.cnt[d >> 9], 1);
                }
            }
            __syncthreads();
            if (tid < NB && sm.b.cnt[tid] > 0)
                sm.b.run[tid] = atomicAdd(&bucket_cnt[tid], sm.b.cnt[tid]);
            if (tid < 128) sm.b.cur[tid] = 0;
            __syncthreads();
#pragma unroll
            for (int k = 0; k < BKT_CHUNK / 256; ++k) {
                int i = base + k * 256 + tid;
                if (i < T) {
                    int d, s;
                    if (i < E) { d = dst[i]; s = src[i]; }
                    else       { d = i - E; s = d; }      // self loop
                    int b = d >> 9;
                    int ofs = atomicAdd(&sm.b.cur[b], 1);
                    int pos = sm.b.run[b] + ofs;
                    if (pos < CAP)
                        staging[(size_t)b * CAP + pos] =
                            (unsigned)s | ((unsigned)(d & 511) << 16);
                }
            }
        } else {
            // ---------------- GEMM part ----------------
#pragma unroll
            for (int p = 0; p < 8; ++p) {
                int f = p * 1024 + tid * 4;               // flat into W[128][64]
                f32x4 w4 = *(const f32x4*)(W + f);
                int k  = f >> 6;
                int c0 = f & 63;
#pragma unroll
                for (int i = 0; i < 4; ++i) {
                    int c = c0 + i;
                    float wv2 = w4[i];
                    unsigned short hi = f2bf(wv2);
                    unsigned short lo = f2bf(wv2 - bf2f(hi));
                    int ks = k ^ ((c & 7) << 3);
                    sm.g.WT[0][c][ks] = hi;
                    sm.g.WT[1][c][ks] = lo;
                }
            }
            __syncthreads();

            int wv = tid >> 6, lane = tid & 63;
            int mrow = lane & 15;
            int kgrp = lane >> 4;
            int row  = vb * 64 + wv * 16 + mrow;
            int rowc = min(row, N - 1);

            f32x4 acc[4];
#pragma unroll
            for (int t = 0; t < 4; ++t) { f32x4 z = {0.f, 0.f, 0.f, 0.f}; acc[t] = z; }

            f32x4 xa[4], xb[4];
#pragma unroll
            for (int s = 0; s < 4; ++s) {
                const float* xp = x + (size_t)rowc * IN_DIM + s * 32 + kgrp * 8;
                xa[s] = *(const f32x4*)xp;
                xb[s] = *(const f32x4*)(xp + 4);
            }

#pragma unroll
            for (int s = 0; s < 4; ++s) {
                bf16x8 ah, al;
#pragma unroll
                for (int i = 0; i < 4; ++i) {
                    unsigned short h0 = f2bf(xa[s][i]);
                    ah[i]     = (short)h0;
                    al[i]     = (short)f2bf(xa[s][i] - bf2f(h0));
                    unsigned short h1 = f2bf(xb[s][i]);
                    ah[4 + i] = (short)h1;
                    al[4 + i] = (short)f2bf(xb[s][i] - bf2f(h1));
                }
                int kbase = s * 32 + kgrp * 8;
#pragma unroll
                for (int t = 0; t < 4; ++t) {
                    int c  = t * 16 + mrow;
                    int ks = kbase ^ ((c & 7) << 3);
                    bf16x8 bh = *(const bf16x8*)&sm.g.WT[0][c][ks];
                    bf16x8 bl = *(const bf16x8*)&sm.g.WT[1][c][ks];
                    acc[t] = __builtin_amdgcn_mfma_f32_16x16x32_bf16(ah, bh, acc[t], 0, 0, 0);
                    acc[t] = __builtin_amdgcn_mfma_f32_16x16x32_bf16(ah, bl, acc[t], 0, 0, 0);
                    acc[t] = __builtin_amdgcn_mfma_f32_16x16x32_bf16(al, bh, acc[t], 0, 0, 0);
                }
            }

            float ai[4], aj[4], aei[4], aej[4];
#pragma unroll
            for (int t = 0; t < 4; ++t) {
                ai[t]  = att_i[t * 16 + mrow];
                aj[t]  = att_j[t * 16 + mrow];
                aei[t] = att_em_i[t * 16 + mrow];
                aej[t] = att_em_j[t * 16 + mrow];
            }
            int crow_base = vb * 64 + wv * 16 + (lane >> 4) * 4;
#pragma unroll
            for (int r = 0; r < 4; ++r) {
                int grow  = crow_base + r;
                int growc = min(grow, N - 1);
                float vi = 0.f, vj = 0.f;
                ushort4 hv;
#pragma unroll
                for (int t = 0; t < 4; ++t) {
                    float gv = acc[t][r];
                    float cv = corrs[(size_t)growc * 64 + t * 16 + mrow];
                    unsigned short h = f2bf(gv);
                    if (t == 0) hv.x = h; else if (t == 1) hv.y = h;
                    else if (t == 2) hv.z = h; else hv.w = h;
                    vi = fmaf(gv, ai[t], fmaf(cv, aei[t], vi));
                    vj = fmaf(gv, aj[t], fmaf(cv, aej[t], vj));
                }
                if (grow < N)
                    *(ushort4*)(g_bf + (size_t)grow * C_DIM + mrow * 4) = hv;
#pragma unroll
                for (int o = 1; o < 16; o <<= 1) {
                    vi += __shfl_xor(vi, o);
                    vj += __shfl_xor(vj, o);
                }
                if (mrow == 0 && grow < N) { s_i[grow] = vi; s_j[grow] = vj; }
            }
        }
        __syncthreads();      // LDS reuse safety across virtual blocks
    }

    grid.sync();

    // ======================= PHASE 2: scatter ==============================
    for (int b = blockIdx.x; b < NB; b += gridDim.x) {
        int t = tid;
        int lo = b << 9;
        int hi = min(lo + 512, N);
        int bcnt = min(bucket_cnt[b], CAP);
        const unsigned int* sb = staging + (size_t)b * CAP;

        sm.s.cnt[2 * t] = 0; sm.s.cnt[2 * t + 1] = 0;
        if (lo + 2 * t     < N) sm.s.si_l[2 * t]     = s_i[lo + 2 * t];
        if (lo + 2 * t + 1 < N) sm.s.si_l[2 * t + 1] = s_i[lo + 2 * t + 1];
        __syncthreads();

        for (int r = t; r < bcnt; r += 256)
            atomicAdd(&sm.s.cnt[(sb[r] >> 16) & 511], 1);
        __syncthreads();

        int a0 = sm.s.cnt[2 * t], a1 = sm.s.cnt[2 * t + 1];
        int s = a0 + a1;
        int lane = t & 63, wv = t >> 6;
        int incl = s;
#pragma unroll
        for (int o = 1; o < 64; o <<= 1) {
            int u = __shfl_up(incl, o);
            if (lane >= o) incl += u;
        }
        if (lane == 63) sm.s.wsum[wv] = incl;
        __syncthreads();
        int woff = 0;
        for (int w = 0; w < wv; ++w) woff += sm.s.wsum[w];
        int ex = woff + incl - s;
        sm.s.off[2 * t] = ex;       sm.s.off[2 * t + 1] = ex + a0;
        sm.s.cur[2 * t] = ex;       sm.s.cur[2 * t + 1] = ex + a0;
        if (t == 255) sm.s.off[512] = woff + incl;
        __syncthreads();

        int rawb = b * CAP;
        for (int i = t; i < hi - lo; i += 256) {
            row_start[lo + i] = rawb + sm.s.off[i];
            row_end[lo + i]   = rawb + sm.s.off[i + 1];
        }
        for (int r = t; r < bcnt; r += 256) {
            unsigned int rec = sb[r];
            int dl   = (rec >> 16) & 511;
            int srcn = rec & 0xFFFFu;
            float a = sm.s.si_l[dl] + s_j[srcn];
            a = (a > 0.f) ? a : 0.2f * a;
            float w = __expf(a);
            int slot = atomicAdd(&sm.s.cur[dl], 1);
            edge_rec[rawb + slot] = ((unsigned)f2bf(w) << 16) | (unsigned)srcn;
        }
        __syncthreads();      // protect si_l/cnt reuse on next iteration
    }

    grid.sync();

    // ======================= PHASE 3: aggregate ============================
    {
        int wave = tid >> 6, lane = tid & 63;
        int grp = lane >> 3;          // edge slot 0..7
        int cl  = lane & 7;           // owns permuted slots cl*8 .. cl*8+7
        int nq = (N + 3) >> 2;
        for (int q = blockIdx.x; q < nq; q += gridDim.x) {
            int n = q * 4 + wave;
            if (n >= N) continue;
            int start = row_start[n];
            int end   = row_end[n];

            float a0 = 0.f, a1 = 0.f, a2 = 0.f, a3 = 0.f;
            float a4 = 0.f, a5 = 0.f, a6 = 0.f, a7 = 0.f, den = 0.f;
#pragma unroll 2
            for (int e0 = start; e0 < end; e0 += 8) {
                int e = e0 + grp;
                if (e < end) {
                    unsigned int rec = edge_rec[e];
                    int   srcn = rec & 0xFFFFu;
                    float w    = bf2f((unsigned short)(rec >> 16));
                    const ushort4* gp = (const ushort4*)(g_bf + (size_t)srcn * C_DIM + (cl << 3));
                    ushort4 g0 = gp[0];
                    ushort4 g1 = gp[1];
                    a0 = fmaf(w, bf2f(g0.x), a0);
                    a1 = fmaf(w, bf2f(g0.y), a1);
                    a2 = fmaf(w, bf2f(g0.z), a2);
                    a3 = fmaf(w, bf2f(g0.w), a3);
                    a4 = fmaf(w, bf2f(g1.x), a4);
                    a5 = fmaf(w, bf2f(g1.y), a5);
                    a6 = fmaf(w, bf2f(g1.z), a6);
                    a7 = fmaf(w, bf2f(g1.w), a7);
                    den += w;
                }
            }
#pragma unroll
            for (int o = 8; o < 64; o <<= 1) {
                a0  += __shfl_xor(a0, o);
                a1  += __shfl_xor(a1, o);
                a2  += __shfl_xor(a2, o);
                a3  += __shfl_xor(a3, o);
                a4  += __shfl_xor(a4, o);
                a5  += __shfl_xor(a5, o);
                a6  += __shfl_xor(a6, o);
                a7  += __shfl_xor(a7, o);
                den += __shfl_xor(den, o);
            }
            if (grp == 0) {
                float inv = 1.f / (den + 1e-16f);
                float av[8] = {a0, a1, a2, a3, a4, a5, a6, a7};
                float* op = out + (size_t)n * C_DIM;
#pragma unroll
                for (int j = 0; j < 8; ++j) {
                    int p  = (cl << 3) + j;                 // permuted slot
                    int ch = ((p & 3) << 4) + (p >> 2);     // real channel
                    op[ch] = fmaxf(fmaf(av[j], inv, bias[ch]), 0.f);
                }
            }
        }
    }
}

// ---------------------------------------------------------------------------
extern "C" void kernel_launch(void* const* d_in, const int* in_sizes, int n_in,
                              void* d_out, int out_size, void* d_ws, size_t ws_size,
                              hipStream_t stream)
{
    const float* x        = (const float*)d_in[0];
    const int*   eidx     = (const int*)  d_in[1];
    const float* corrs    = (const float*)d_in[2];
    const float* W        = (const float*)d_in[3];
    const float* att_i    = (const float*)d_in[4];
    const float* att_j    = (const float*)d_in[5];
    const float* att_em_i = (const float*)d_in[6];
    const float* att_em_j = (const float*)d_in[7];
    const float* bias     = (const float*)d_in[8];
    float* out = (float*)d_out;

    int N = in_sizes[0] / IN_DIM;
    int E = in_sizes[1] / 2;
    const int* src = eidx;
    const int* dst = eidx + E;

    int T  = E + N;
    int NB = (N + 511) >> 9;                       // 512 nodes per bucket
    int CAP = ((T + NB - 1) / NB);
    CAP = CAP + CAP / 4;                           // 1.25x slack
    CAP = (CAP + 63) & ~63;

    char* ws = (char*)d_ws;
    size_t off = 0;
    auto alloc = [&](size_t bytes) -> void* {
        void* p = ws + off;
        off += (bytes + 255) & ~(size_t)255;
        return p;
    };
    unsigned short* g_bf = (unsigned short*)alloc((size_t)N * C_DIM * sizeof(unsigned short));
    float* s_i       = (float*)alloc((size_t)N * sizeof(float));
    float* s_j       = (float*)alloc((size_t)N * sizeof(float));
    unsigned int* staging  = (unsigned int*)alloc((size_t)NB * CAP * sizeof(unsigned int));
    unsigned int* edge_rec = (unsigned int*)alloc((size_t)NB * CAP * sizeof(unsigned int));
    int*   row_start = (int*)alloc((size_t)N * sizeof(int));
    int*   row_end   = (int*)alloc((size_t)N * sizeof(int));
    int*   bucket_cnt= (int*)alloc(128 * sizeof(int));
    (void)ws_size; (void)n_in; (void)out_size;

    hipMemsetAsync(bucket_cnt, 0, 128 * sizeof(int), stream);

    int GB = (N + 63) / 64;                        // gemm virtual blocks
    int BB = (T + BKT_CHUNK - 1) / BKT_CHUNK;      // bucket virtual blocks

    // Co-residency bound for the cooperative launch (MI355X: 256 CUs).
    int occ = 0;
    hipOccupancyMaxActiveBlocksPerMultiprocessor(&occ, k_fused, 256, 0);
    if (occ < 1) occ = 1;
    int maxco = occ * 256;
    int need  = GB + BB;
    int gridn = need < maxco ? need : maxco;

    void* args[] = {
        (void*)&x, (void*)&W, (void*)&corrs,
        (void*)&att_i, (void*)&att_j, (void*)&att_em_i, (void*)&att_em_j,
        (void*)&g_bf, (void*)&s_i, (void*)&s_j,
        (void*)&src, (void*)&dst,
        (void*)&N, (void*)&E, (void*)&GB, (void*)&BB, (void*)&NB, (void*)&CAP,
        (void*)&bucket_cnt, (void*)&staging, (void*)&edge_rec,
        (void*)&row_start, (void*)&row_end,
        (void*)&bias, (void*)&out
    };
    hipLaunchCooperativeKernel((void*)k_fused, dim3(gridn), dim3(256),
                               args, 0, stream);
}

// Round 19
// 75.320 us; speedup vs baseline: 3.4618x; 3.4452x over previous
//
#include <hip/hip_runtime.h>
#include <hip/hip_bf16.h>
#include <math.h>

#define IN_DIM 128
#define C_DIM 64
#define BKT_CHUNK 4096

typedef short bf16x8 __attribute__((ext_vector_type(8)));
typedef float f32x4 __attribute__((ext_vector_type(4)));

static __device__ __forceinline__ unsigned short f2bf(float f) {
    unsigned int u = __float_as_uint(f);
    u += 0x7FFFu + ((u >> 16) & 1u);          // round-to-nearest-even
    return (unsigned short)(u >> 16);
}
static __device__ __forceinline__ float bf2f(unsigned short h) {
    return __uint_as_float(((unsigned int)h) << 16);
}

// ---------------------------------------------------------------------------
// FUSED kernel: blockIdx < GB  -> GEMM (g = x@W bf16 MFMA, 2-term split:
//   bf16(x)·(W_hi + W_lo) — x-lo term dropped, adds only ~0.003 abs error)
//               blockIdx >= GB -> bucket-partition of the edge list
//                                 (256 nodes/bucket, NB <= 256)
// ---------------------------------------------------------------------------
__global__ __launch_bounds__(256) void k_gemm_bucket(
    const float* __restrict__ x, const float* __restrict__ W,
    const float* __restrict__ corrs,
    const float* __restrict__ att_i, const float* __restrict__ att_j,
    const float* __restrict__ att_em_i, const float* __restrict__ att_em_j,
    unsigned short* __restrict__ g_bf, float* __restrict__ s_i, float* __restrict__ s_j,
    int N, int GB,
    const int* __restrict__ src, const int* __restrict__ dst,
    int E, int NB, int CAP,
    int* __restrict__ bucket_cnt, unsigned int* __restrict__ staging)
{
    __shared__ __attribute__((aligned(16))) unsigned short WT[2][64][128]; // 32KB
    __shared__ int cnt[256];
    __shared__ int run[256];
    __shared__ int cur[256];

    int tid = threadIdx.x;

    if (blockIdx.x >= GB) {
        // ---------------- bucket part ----------------
        cnt[tid] = 0;
        __syncthreads();

        int T = E + N;
        int base = (blockIdx.x - GB) * BKT_CHUNK;
#pragma unroll
        for (int k = 0; k < BKT_CHUNK / 256; ++k) {
            int i = base + k * 256 + tid;
            if (i < T) {
                int d = (i < E) ? dst[i] : (i - E);
                atomicAdd(&cnt[d >> 8], 1);
            }
        }
        __syncthreads();
        if (tid < NB && cnt[tid] > 0) run[tid] = atomicAdd(&bucket_cnt[tid], cnt[tid]);
        cur[tid] = 0;
        __syncthreads();
#pragma unroll
        for (int k = 0; k < BKT_CHUNK / 256; ++k) {
            int i = base + k * 256 + tid;
            if (i < T) {
                int d, s;
                if (i < E) { d = dst[i]; s = src[i]; }
                else       { d = i - E; s = d; }      // self loop
                int b = d >> 8;
                int ofs = atomicAdd(&cur[b], 1);
                int pos = run[b] + ofs;
                if (pos < CAP)
                    staging[(size_t)b * CAP + pos] =
                        (unsigned)s | ((unsigned)(d & 255) << 16);
            }
        }
        return;
    }

    // ---------------- GEMM part ----------------
#pragma unroll
    for (int p = 0; p < 8; ++p) {
        int f = p * 1024 + tid * 4;               // flat into W[128][64]
        f32x4 w4 = *(const f32x4*)(W + f);
        int k  = f >> 6;
        int c0 = f & 63;
#pragma unroll
        for (int i = 0; i < 4; ++i) {
            int c = c0 + i;
            float wv = w4[i];
            unsigned short hi = f2bf(wv);
            unsigned short lo = f2bf(wv - bf2f(hi));
            int ks = k ^ ((c & 7) << 3);
            WT[0][c][ks] = hi;
            WT[1][c][ks] = lo;
        }
    }
    __syncthreads();

    int wv = tid >> 6, lane = tid & 63;
    int mrow = lane & 15;
    int kgrp = lane >> 4;
    int row  = blockIdx.x * 64 + wv * 16 + mrow;
    int rowc = min(row, N - 1);

    f32x4 acc[4];
#pragma unroll
    for (int t = 0; t < 4; ++t) { f32x4 z = {0.f, 0.f, 0.f, 0.f}; acc[t] = z; }

    f32x4 xa[4], xb[4];
#pragma unroll
    for (int s = 0; s < 4; ++s) {
        const float* xp = x + (size_t)rowc * IN_DIM + s * 32 + kgrp * 8;
        xa[s] = *(const f32x4*)xp;
        xb[s] = *(const f32x4*)(xp + 4);
    }

#pragma unroll
    for (int s = 0; s < 4; ++s) {
        bf16x8 ah;
#pragma unroll
        for (int i = 0; i < 4; ++i) {
            ah[i]     = (short)f2bf(xa[s][i]);
            ah[4 + i] = (short)f2bf(xb[s][i]);
        }
        int kbase = s * 32 + kgrp * 8;
#pragma unroll
        for (int t = 0; t < 4; ++t) {
            int c  = t * 16 + mrow;
            int ks = kbase ^ ((c & 7) << 3);
            bf16x8 bh = *(const bf16x8*)&WT[0][c][ks];
            bf16x8 bl = *(const bf16x8*)&WT[1][c][ks];
            acc[t] = __builtin_amdgcn_mfma_f32_16x16x32_bf16(ah, bh, acc[t], 0, 0, 0);
            acc[t] = __builtin_amdgcn_mfma_f32_16x16x32_bf16(ah, bl, acc[t], 0, 0, 0);
        }
    }

    float ai[4], aj[4], aei[4], aej[4];
#pragma unroll
    for (int t = 0; t < 4; ++t) {
        ai[t]  = att_i[t * 16 + mrow];
        aj[t]  = att_j[t * 16 + mrow];
        aei[t] = att_em_i[t * 16 + mrow];
        aej[t] = att_em_j[t * 16 + mrow];
    }
    int crow_base = blockIdx.x * 64 + wv * 16 + (lane >> 4) * 4;
#pragma unroll
    for (int r = 0; r < 4; ++r) {
        int grow  = crow_base + r;
        int growc = min(grow, N - 1);
        float vi = 0.f, vj = 0.f;
        ushort4 hv;
#pragma unroll
        for (int t = 0; t < 4; ++t) {
            float gv = acc[t][r];
            float cv = corrs[(size_t)growc * 64 + t * 16 + mrow];
            unsigned short h = f2bf(gv);
            if (t == 0) hv.x = h; else if (t == 1) hv.y = h;
            else if (t == 2) hv.z = h; else hv.w = h;
            vi = fmaf(gv, ai[t], fmaf(cv, aei[t], vi));
            vj = fmaf(gv, aj[t], fmaf(cv, aej[t], vj));
        }
        if (grow < N)
            *(ushort4*)(g_bf + (size_t)grow * C_DIM + mrow * 4) = hv;
#pragma unroll
        for (int o = 1; o < 16; o <<= 1) {
            vi += __shfl_xor(vi, o);
            vj += __shfl_xor(vj, o);
        }
        if (mrow == 0 && grow < N) { s_i[grow] = vi; s_j[grow] = vj; }
    }
}

// ---------------------------------------------------------------------------
// Phase 2: one block per bucket (256 nodes). LDS count -> scan ->
// row_start/row_end -> scatter records with PRECOMPUTED bf16 weight:
// rec = (bf16(w)<<16)|src, w = exp(leaky(s_i[d]+s_j[s])).
// REQUIRES N <= 65536 (src in 16 bits).
// ---------------------------------------------------------------------------
__global__ __launch_bounds__(256) void k_scatter(
    const unsigned int* __restrict__ staging, const int* __restrict__ bucket_cnt,
    int N, int CAP,
    const float* __restrict__ s_i, const float* __restrict__ s_j,
    int* __restrict__ row_start, int* __restrict__ row_end,
    unsigned int* __restrict__ edge_rec)
{
    __shared__ int cnt[256];
    __shared__ int off[257];
    __shared__ int cur[256];
    __shared__ int wsum[4];
    __shared__ float si_l[256];

    int b = blockIdx.x, t = threadIdx.x;
    int lo = b << 8;
    int hi = min(lo + 256, N);
    int bcnt = min(bucket_cnt[b], CAP);
    const unsigned int* sb = staging + (size_t)b * CAP;

    cnt[t] = 0;
    if (lo + t < N) si_l[t] = s_i[lo + t];
    __syncthreads();

    for (int r = t; r < bcnt; r += 256)
        atomicAdd(&cnt[(sb[r] >> 16) & 255], 1);
    __syncthreads();

    // exclusive scan of cnt[0..256); thread t owns cnt[t]
    int s = cnt[t];
    int lane = t & 63, wv = t >> 6;
    int incl = s;
#pragma unroll
    for (int o = 1; o < 64; o <<= 1) {
        int u = __shfl_up(incl, o);
        if (lane >= o) incl += u;
    }
    if (lane == 63) wsum[wv] = incl;
    __syncthreads();
    int woff = 0;
    for (int w = 0; w < wv; ++w) woff += wsum[w];
    int ex = woff + incl - s;
    off[t] = ex;
    cur[t] = ex;
    if (t == 255) off[256] = woff + incl;
    __syncthreads();

    int rawb = b * CAP;
    for (int i = t; i < hi - lo; i += 256) {
        row_start[lo + i] = rawb + off[i];
        row_end[lo + i]   = rawb + off[i + 1];
    }
    for (int r = t; r < bcnt; r += 256) {
        unsigned int rec = sb[r];
        int dl   = (rec >> 16) & 255;
        int srcn = rec & 0xFFFFu;
        float a = si_l[dl] + s_j[srcn];
        a = (a > 0.f) ? a : 0.2f * a;
        float w = __expf(a);
        int slot = atomicAdd(&cur[dl], 1);
        edge_rec[rawb + slot] = ((unsigned)f2bf(w) << 16) | (unsigned)srcn;
    }
}

// ---------------------------------------------------------------------------
// Fused single-pass softmax-aggregate. One wave per node; max-free softmax.
// 8 edges x 8 lanes; lane owns 8 permuted channel slots (2 x ushort4).
// Inner loop: 4B record -> 16B gather -> 8 fma + den. No exp, no s_j gather.
// ---------------------------------------------------------------------------
__global__ __launch_bounds__(256) void k_aggregate(
    const unsigned short* __restrict__ g_bf,
    const int* __restrict__ row_start, const int* __restrict__ row_end,
    const unsigned int* __restrict__ edge_rec,
    const float* __restrict__ bias, float* __restrict__ out, int N)
{
    int wave = threadIdx.x >> 6, lane = threadIdx.x & 63;
    int n = blockIdx.x * 4 + wave;
    if (n >= N) return;

    int start = row_start[n];
    int end   = row_end[n];

    int grp = lane >> 3;          // edge slot 0..7
    int cl  = lane & 7;           // owns permuted slots cl*8 .. cl*8+7
    float a0 = 0.f, a1 = 0.f, a2 = 0.f, a3 = 0.f;
    float a4 = 0.f, a5 = 0.f, a6 = 0.f, a7 = 0.f, den = 0.f;
#pragma unroll 2
    for (int e0 = start; e0 < end; e0 += 8) {
        int e = e0 + grp;
        if (e < end) {
            unsigned int rec = edge_rec[e];        // broadcast within 8-lane group
            int   srcn = rec & 0xFFFFu;
            float w    = bf2f((unsigned short)(rec >> 16));
            const ushort4* gp = (const ushort4*)(g_bf + (size_t)srcn * C_DIM + (cl << 3));
            ushort4 g0 = gp[0];
            ushort4 g1 = gp[1];
            a0 = fmaf(w, bf2f(g0.x), a0);
            a1 = fmaf(w, bf2f(g0.y), a1);
            a2 = fmaf(w, bf2f(g0.z), a2);
            a3 = fmaf(w, bf2f(g0.w), a3);
            a4 = fmaf(w, bf2f(g1.x), a4);
            a5 = fmaf(w, bf2f(g1.y), a5);
            a6 = fmaf(w, bf2f(g1.z), a6);
            a7 = fmaf(w, bf2f(g1.w), a7);
            den += w;
        }
    }
#pragma unroll
    for (int o = 8; o < 64; o <<= 1) {
        a0  += __shfl_xor(a0, o);
        a1  += __shfl_xor(a1, o);
        a2  += __shfl_xor(a2, o);
        a3  += __shfl_xor(a3, o);
        a4  += __shfl_xor(a4, o);
        a5  += __shfl_xor(a5, o);
        a6  += __shfl_xor(a6, o);
        a7  += __shfl_xor(a7, o);
        den += __shfl_xor(den, o);
    }
    if (grp == 0) {
        float inv = 1.f / (den + 1e-16f);
        float av[8] = {a0, a1, a2, a3, a4, a5, a6, a7};
        float* op = out + (size_t)n * C_DIM;
#pragma unroll
        for (int j = 0; j < 8; ++j) {
            int p  = (cl << 3) + j;                 // permuted slot
            int ch = ((p & 3) << 4) + (p >> 2);     // real channel
            op[ch] = fmaxf(fmaf(av[j], inv, bias[ch]), 0.f);
        }
    }
}

// ---------------------------------------------------------------------------
extern "C" void kernel_launch(void* const* d_in, const int* in_sizes, int n_in,
                              void* d_out, int out_size, void* d_ws, size_t ws_size,
                              hipStream_t stream)
{
    const float* x        = (const float*)d_in[0];
    const int*   eidx     = (const int*)  d_in[1];
    const float* corrs    = (const float*)d_in[2];
    const float* W        = (const float*)d_in[3];
    const float* att_i    = (const float*)d_in[4];
    const float* att_j    = (const float*)d_in[5];
    const float* att_em_i = (const float*)d_in[6];
    const float* att_em_j = (const float*)d_in[7];
    const float* bias     = (const float*)d_in[8];
    float* out = (float*)d_out;

    int N = in_sizes[0] / IN_DIM;
    int E = in_sizes[1] / 2;
    const int* src = eidx;
    const int* dst = eidx + E;

    int T  = E + N;
    int NB = (N + 255) >> 8;                       // 256 nodes per bucket
    int CAP = ((T + NB - 1) / NB);
    CAP = CAP + CAP / 4;                           // 1.25x slack
    CAP = (CAP + 63) & ~63;

    char* ws = (char*)d_ws;
    size_t off = 0;
    auto alloc = [&](size_t bytes) -> void* {
        void* p = ws + off;
        off += (bytes + 255) & ~(size_t)255;
        return p;
    };
    unsigned short* g_bf = (unsigned short*)alloc((size_t)N * C_DIM * sizeof(unsigned short));
    float* s_i       = (float*)alloc((size_t)N * sizeof(float));
    float* s_j       = (float*)alloc((size_t)N * sizeof(float));
    unsigned int* staging  = (unsigned int*)alloc((size_t)NB * CAP * sizeof(unsigned int));
    unsigned int* edge_rec = (unsigned int*)alloc((size_t)NB * CAP * sizeof(unsigned int));
    int*   row_start = (int*)alloc((size_t)N * sizeof(int));
    int*   row_end   = (int*)alloc((size_t)N * sizeof(int));
    int*   bucket_cnt= (int*)alloc(256 * sizeof(int));
    (void)ws_size; (void)n_in; (void)out_size;

    hipMemsetAsync(bucket_cnt, 0, 256 * sizeof(int), stream);

    int GB = (N + 63) / 64;                        // gemm blocks
    int BB = (T + BKT_CHUNK - 1) / BKT_CHUNK;      // bucket blocks
    k_gemm_bucket<<<GB + BB, 256, 0, stream>>>(
        x, W, corrs, att_i, att_j, att_em_i, att_em_j, g_bf, s_i, s_j,
        N, GB, src, dst, E, NB, CAP, bucket_cnt, staging);

    k_scatter<<<NB, 256, 0, stream>>>(
        staging, bucket_cnt, N, CAP, s_i, s_j, row_start, row_end, edge_rec);

    k_aggregate<<<(N + 3) / 4, 256, 0, stream>>>(
        g_bf, row_start, row_end, edge_rec, bias, out, N);
}

// Round 20
// 73.983 us; speedup vs baseline: 3.5244x; 1.0181x over previous
//
#include <hip/hip_runtime.h>
#include <hip/hip_bf16.h>
#include <math.h>

#define IN_DIM 128
#define C_DIM 64
#define BKT_CHUNK 4096
#define AGG_LDS_RECS 1280

typedef short bf16x8 __attribute__((ext_vector_type(8)));
typedef float f32x4 __attribute__((ext_vector_type(4)));

static __device__ __forceinline__ unsigned short f2bf(float f) {
    unsigned int u = __float_as_uint(f);
    u += 0x7FFFu + ((u >> 16) & 1u);          // round-to-nearest-even
    return (unsigned short)(u >> 16);
}
static __device__ __forceinline__ float bf2f(unsigned short h) {
    return __uint_as_float(((unsigned int)h) << 16);
}

// ---------------------------------------------------------------------------
// FUSED kernel: blockIdx < GB  -> GEMM, 128 rows/block (two 64-row halves
//   reusing the staged W: halves the per-block W stage+convert redundancy).
//   2-term split: bf16(x)·(W_hi + W_lo).
//               blockIdx >= GB -> bucket-partition (256 nodes/bucket).
// ---------------------------------------------------------------------------
__global__ __launch_bounds__(256) void k_gemm_bucket(
    const float* __restrict__ x, const float* __restrict__ W,
    const float* __restrict__ corrs,
    const float* __restrict__ att_i, const float* __restrict__ att_j,
    const float* __restrict__ att_em_i, const float* __restrict__ att_em_j,
    unsigned short* __restrict__ g_bf, float* __restrict__ s_i, float* __restrict__ s_j,
    int N, int GB,
    const int* __restrict__ src, const int* __restrict__ dst,
    int E, int NB, int CAP,
    int* __restrict__ bucket_cnt, unsigned int* __restrict__ staging)
{
    __shared__ __attribute__((aligned(16))) unsigned short WT[2][64][128]; // 32KB
    __shared__ int cnt[256];
    __shared__ int run[256];
    __shared__ int cur[256];

    int tid = threadIdx.x;

    if (blockIdx.x >= GB) {
        // ---------------- bucket part ----------------
        cnt[tid] = 0;
        __syncthreads();

        int T = E + N;
        int base = (blockIdx.x - GB) * BKT_CHUNK;
#pragma unroll
        for (int k = 0; k < BKT_CHUNK / 256; ++k) {
            int i = base + k * 256 + tid;
            if (i < T) {
                int d = (i < E) ? dst[i] : (i - E);
                atomicAdd(&cnt[d >> 8], 1);
            }
        }
        __syncthreads();
        if (tid < NB && cnt[tid] > 0) run[tid] = atomicAdd(&bucket_cnt[tid], cnt[tid]);
        cur[tid] = 0;
        __syncthreads();
#pragma unroll
        for (int k = 0; k < BKT_CHUNK / 256; ++k) {
            int i = base + k * 256 + tid;
            if (i < T) {
                int d, s;
                if (i < E) { d = dst[i]; s = src[i]; }
                else       { d = i - E; s = d; }      // self loop
                int b = d >> 8;
                int ofs = atomicAdd(&cur[b], 1);
                int pos = run[b] + ofs;
                if (pos < CAP)
                    staging[(size_t)b * CAP + pos] =
                        (unsigned)s | ((unsigned)(d & 255) << 16);
            }
        }
        return;
    }

    // ---------------- GEMM part (128 rows per block, 2 halves) -------------
#pragma unroll
    for (int p = 0; p < 8; ++p) {
        int f = p * 1024 + tid * 4;               // flat into W[128][64]
        f32x4 w4 = *(const f32x4*)(W + f);
        int k  = f >> 6;
        int c0 = f & 63;
#pragma unroll
        for (int i = 0; i < 4; ++i) {
            int c = c0 + i;
            float wv = w4[i];
            unsigned short hi = f2bf(wv);
            unsigned short lo = f2bf(wv - bf2f(hi));
            int ks = k ^ ((c & 7) << 3);
            WT[0][c][ks] = hi;
            WT[1][c][ks] = lo;
        }
    }
    __syncthreads();

    int wv = tid >> 6, lane = tid & 63;
    int mrow = lane & 15;
    int kgrp = lane >> 4;

    float ai[4], aj[4], aei[4], aej[4];
#pragma unroll
    for (int t = 0; t < 4; ++t) {
        ai[t]  = att_i[t * 16 + mrow];
        aj[t]  = att_j[t * 16 + mrow];
        aei[t] = att_em_i[t * 16 + mrow];
        aej[t] = att_em_j[t * 16 + mrow];
    }

    for (int half = 0; half < 2; ++half) {
        int row = blockIdx.x * 128 + half * 64 + wv * 16 + mrow;
        int rowc = min(row, N - 1);

        f32x4 acc[4];
#pragma unroll
        for (int t = 0; t < 4; ++t) { f32x4 z = {0.f, 0.f, 0.f, 0.f}; acc[t] = z; }

        f32x4 xa[4], xb[4];
#pragma unroll
        for (int s = 0; s < 4; ++s) {
            const float* xp = x + (size_t)rowc * IN_DIM + s * 32 + kgrp * 8;
            xa[s] = *(const f32x4*)xp;
            xb[s] = *(const f32x4*)(xp + 4);
        }

#pragma unroll
        for (int s = 0; s < 4; ++s) {
            bf16x8 ah;
#pragma unroll
            for (int i = 0; i < 4; ++i) {
                ah[i]     = (short)f2bf(xa[s][i]);
                ah[4 + i] = (short)f2bf(xb[s][i]);
            }
            int kbase = s * 32 + kgrp * 8;
#pragma unroll
            for (int t = 0; t < 4; ++t) {
                int c  = t * 16 + mrow;
                int ks = kbase ^ ((c & 7) << 3);
                bf16x8 bh = *(const bf16x8*)&WT[0][c][ks];
                bf16x8 bl = *(const bf16x8*)&WT[1][c][ks];
                acc[t] = __builtin_amdgcn_mfma_f32_16x16x32_bf16(ah, bh, acc[t], 0, 0, 0);
                acc[t] = __builtin_amdgcn_mfma_f32_16x16x32_bf16(ah, bl, acc[t], 0, 0, 0);
            }
        }

        int crow_base = blockIdx.x * 128 + half * 64 + wv * 16 + (lane >> 4) * 4;
#pragma unroll
        for (int r = 0; r < 4; ++r) {
            int grow  = crow_base + r;
            int growc = min(grow, N - 1);
            float vi = 0.f, vj = 0.f;
            ushort4 hv;
#pragma unroll
            for (int t = 0; t < 4; ++t) {
                float gv = acc[t][r];
                float cv = corrs[(size_t)growc * 64 + t * 16 + mrow];
                unsigned short h = f2bf(gv);
                if (t == 0) hv.x = h; else if (t == 1) hv.y = h;
                else if (t == 2) hv.z = h; else hv.w = h;
                vi = fmaf(gv, ai[t], fmaf(cv, aei[t], vi));
                vj = fmaf(gv, aj[t], fmaf(cv, aej[t], vj));
            }
            if (grow < N)
                *(ushort4*)(g_bf + (size_t)grow * C_DIM + mrow * 4) = hv;
#pragma unroll
            for (int o = 1; o < 16; o <<= 1) {
                vi += __shfl_xor(vi, o);
                vj += __shfl_xor(vj, o);
            }
            if (mrow == 0 && grow < N) { s_i[grow] = vi; s_j[grow] = vj; }
        }
    }
}

// ---------------------------------------------------------------------------
// Phase 2: one block per bucket (256 nodes). LDS count -> scan ->
// row_start/row_end -> scatter records with PRECOMPUTED bf16 weight:
// rec = (bf16(w)<<16)|src, w = exp(leaky(s_i[d]+s_j[s])).
// REQUIRES N <= 65536 (src in 16 bits).
// ---------------------------------------------------------------------------
__global__ __launch_bounds__(256) void k_scatter(
    const unsigned int* __restrict__ staging, const int* __restrict__ bucket_cnt,
    int N, int CAP,
    const float* __restrict__ s_i, const float* __restrict__ s_j,
    int* __restrict__ row_start, int* __restrict__ row_end,
    unsigned int* __restrict__ edge_rec)
{
    __shared__ int cnt[256];
    __shared__ int off[257];
    __shared__ int cur[256];
    __shared__ int wsum[4];
    __shared__ float si_l[256];

    int b = blockIdx.x, t = threadIdx.x;
    int lo = b << 8;
    int hi = min(lo + 256, N);
    int bcnt = min(bucket_cnt[b], CAP);
    const unsigned int* sb = staging + (size_t)b * CAP;

    cnt[t] = 0;
    if (lo + t < N) si_l[t] = s_i[lo + t];
    __syncthreads();

    for (int r = t; r < bcnt; r += 256)
        atomicAdd(&cnt[(sb[r] >> 16) & 255], 1);
    __syncthreads();

    int s = cnt[t];
    int lane = t & 63, wv = t >> 6;
    int incl = s;
#pragma unroll
    for (int o = 1; o < 64; o <<= 1) {
        int u = __shfl_up(incl, o);
        if (lane >= o) incl += u;
    }
    if (lane == 63) wsum[wv] = incl;
    __syncthreads();
    int woff = 0;
    for (int w = 0; w < wv; ++w) woff += wsum[w];
    int ex = woff + incl - s;
    off[t] = ex;
    cur[t] = ex;
    if (t == 255) off[256] = woff + incl;
    __syncthreads();

    int rawb = b * CAP;
    for (int i = t; i < hi - lo; i += 256) {
        row_start[lo + i] = rawb + off[i];
        row_end[lo + i]   = rawb + off[i + 1];
    }
    for (int r = t; r < bcnt; r += 256) {
        unsigned int rec = sb[r];
        int dl   = (rec >> 16) & 255;
        int srcn = rec & 0xFFFFu;
        float a = si_l[dl] + s_j[srcn];
        a = (a > 0.f) ? a : 0.2f * a;
        float w = __expf(a);
        int slot = atomicAdd(&cur[dl], 1);
        edge_rec[rawb + slot] = ((unsigned)f2bf(w) << 16) | (unsigned)srcn;
    }
}

// ---------------------------------------------------------------------------
// Fused single-pass softmax-aggregate. One wave per node; max-free softmax.
// R20: block's 4 nodes own ONE contiguous record range inside a bucket
// (4 | 256); coalesced-preload it to LDS so the inner loop's first hop is a
// ~20cy LDS broadcast, not a ~200cy L2 read. Fallback to global if >1280.
// ---------------------------------------------------------------------------
__global__ __launch_bounds__(256) void k_aggregate(
    const unsigned short* __restrict__ g_bf,
    const int* __restrict__ row_start, const int* __restrict__ row_end,
    const unsigned int* __restrict__ edge_rec,
    const float* __restrict__ bias, float* __restrict__ out, int N)
{
    __shared__ unsigned int recs[AGG_LDS_RECS];

    int tid  = threadIdx.x;
    int n0 = blockIdx.x * 4;
    if (n0 >= N) return;
    int nlast = min(n0 + 3, N - 1);

    int s0 = row_start[n0];
    int e3 = row_end[nlast];
    int rc = e3 - s0;
    bool lds_ok = (rc <= AGG_LDS_RECS);
    if (lds_ok) {
        for (int i = tid; i < rc; i += 256)
            recs[i] = edge_rec[s0 + i];
    }
    __syncthreads();

    int wave = tid >> 6, lane = tid & 63;
    int n = n0 + wave;
    if (n >= N) return;

    int start = row_start[n];
    int end   = row_end[n];

    int grp = lane >> 3;          // edge slot 0..7
    int cl  = lane & 7;           // owns permuted slots cl*8 .. cl*8+7
    float a0 = 0.f, a1 = 0.f, a2 = 0.f, a3 = 0.f;
    float a4 = 0.f, a5 = 0.f, a6 = 0.f, a7 = 0.f, den = 0.f;
#pragma unroll 2
    for (int e0 = start; e0 < end; e0 += 8) {
        int e = e0 + grp;
        if (e < end) {
            unsigned int rec = lds_ok ? recs[e - s0] : edge_rec[e];
            int   srcn = rec & 0xFFFFu;
            float w    = bf2f((unsigned short)(rec >> 16));
            const ushort4* gp = (const ushort4*)(g_bf + (size_t)srcn * C_DIM + (cl << 3));
            ushort4 g0 = gp[0];
            ushort4 g1 = gp[1];
            a0 = fmaf(w, bf2f(g0.x), a0);
            a1 = fmaf(w, bf2f(g0.y), a1);
            a2 = fmaf(w, bf2f(g0.z), a2);
            a3 = fmaf(w, bf2f(g0.w), a3);
            a4 = fmaf(w, bf2f(g1.x), a4);
            a5 = fmaf(w, bf2f(g1.y), a5);
            a6 = fmaf(w, bf2f(g1.z), a6);
            a7 = fmaf(w, bf2f(g1.w), a7);
            den += w;
        }
    }
#pragma unroll
    for (int o = 8; o < 64; o <<= 1) {
        a0  += __shfl_xor(a0, o);
        a1  += __shfl_xor(a1, o);
        a2  += __shfl_xor(a2, o);
        a3  += __shfl_xor(a3, o);
        a4  += __shfl_xor(a4, o);
        a5  += __shfl_xor(a5, o);
        a6  += __shfl_xor(a6, o);
        a7  += __shfl_xor(a7, o);
        den += __shfl_xor(den, o);
    }
    if (grp == 0) {
        float inv = 1.f / (den + 1e-16f);
        float av[8] = {a0, a1, a2, a3, a4, a5, a6, a7};
        float* op = out + (size_t)n * C_DIM;
#pragma unroll
        for (int j = 0; j < 8; ++j) {
            int p  = (cl << 3) + j;                 // permuted slot
            int ch = ((p & 3) << 4) + (p >> 2);     // real channel
            op[ch] = fmaxf(fmaf(av[j], inv, bias[ch]), 0.f);
        }
    }
}

// ---------------------------------------------------------------------------
extern "C" void kernel_launch(void* const* d_in, const int* in_sizes, int n_in,
                              void* d_out, int out_size, void* d_ws, size_t ws_size,
                              hipStream_t stream)
{
    const float* x        = (const float*)d_in[0];
    const int*   eidx     = (const int*)  d_in[1];
    const float* corrs    = (const float*)d_in[2];
    const float* W        = (const float*)d_in[3];
    const float* att_i    = (const float*)d_in[4];
    const float* att_j    = (const float*)d_in[5];
    const float* att_em_i = (const float*)d_in[6];
    const float* att_em_j = (const float*)d_in[7];
    const float* bias     = (const float*)d_in[8];
    float* out = (float*)d_out;

    int N = in_sizes[0] / IN_DIM;
    int E = in_sizes[1] / 2;
    const int* src = eidx;
    const int* dst = eidx + E;

    int T  = E + N;
    int NB = (N + 255) >> 8;                       // 256 nodes per bucket
    int CAP = ((T + NB - 1) / NB);
    CAP = CAP + CAP / 4;                           // 1.25x slack
    CAP = (CAP + 63) & ~63;

    char* ws = (char*)d_ws;
    size_t off = 0;
    auto alloc = [&](size_t bytes) -> void* {
        void* p = ws + off;
        off += (bytes + 255) & ~(size_t)255;
        return p;
    };
    unsigned short* g_bf = (unsigned short*)alloc((size_t)N * C_DIM * sizeof(unsigned short));
    float* s_i       = (float*)alloc((size_t)N * sizeof(float));
    float* s_j       = (float*)alloc((size_t)N * sizeof(float));
    unsigned int* staging  = (unsigned int*)alloc((size_t)NB * CAP * sizeof(unsigned int));
    unsigned int* edge_rec = (unsigned int*)alloc((size_t)NB * CAP * sizeof(unsigned int));
    int*   row_start = (int*)alloc((size_t)N * sizeof(int));
    int*   row_end   = (int*)alloc((size_t)N * sizeof(int));
    int*   bucket_cnt= (int*)alloc(256 * sizeof(int));
    (void)ws_size; (void)n_in; (void)out_size;

    hipMemsetAsync(bucket_cnt, 0, 256 * sizeof(int), stream);

    int GB = (N + 127) / 128;                      // gemm blocks (128 rows each)
    int BB = (T + BKT_CHUNK - 1) / BKT_CHUNK;      // bucket blocks
    k_gemm_bucket<<<GB + BB, 256, 0, stream>>>(
        x, W, corrs, att_i, att_j, att_em_i, att_em_j, g_bf, s_i, s_j,
        N, GB, src, dst, E, NB, CAP, bucket_cnt, staging);

    k_scatter<<<NB, 256, 0, stream>>>(
        staging, bucket_cnt, N, CAP, s_i, s_j, row_start, row_end, edge_rec);

    k_aggregate<<<(N + 3) / 4, 256, 0, stream>>>(
        g_bf, row_start, row_end, edge_rec, bias, out, N);
}